// Round 1
// baseline (683.655 us; speedup 1.0000x reference)
//
#include <hip/hip_runtime.h>
#include <cmath>

#define NPOSN 1024   // 32*32 positions
#define NCH   256    // channels
#define NB    16     // batch
#define MTOT  (NB*NPOSN)  // 16384 rows

// ---------------------------------------------------------------------------
// Kernel 1: relative-position-bias MLP table.
// tab[p][h] = 16*sigmoid( mlp2( relu( mlp1( sign(g)*(1-exp(-|g|)) ) ) ) )
// p = ph*63+pw over the 63x63 relative-offset grid.
// ---------------------------------------------------------------------------
__global__ void bias_mlp_kernel(const float* __restrict__ w1,
                                const float* __restrict__ b1,
                                const float* __restrict__ w2,
                                float* __restrict__ tab) {
  __shared__ float sw1[256];
  __shared__ float sb1[128];
  __shared__ float sw2[1024];
  int t = threadIdx.x;
  sw1[t] = w1[t];
  if (t < 128) sb1[t] = b1[t];
  for (int i = t; i < 1024; i += 256) sw2[i] = w2[i];
  __syncthreads();
  int p = blockIdx.x * 256 + t;
  if (p >= 3969) return;
  int ph = p / 63, pw = p % 63;
  float gh = (float)(ph - 31) * (1.0f / 31.0f);
  float gw = (float)(pw - 31) * (1.0f / 31.0f);
  float t0 = gh * 3.2f, t1 = gw * 3.2f;
  t0 = copysignf(1.0f - __expf(-fabsf(t0)), t0);
  t1 = copysignf(1.0f - __expf(-fabsf(t1)), t1);
  float acc[8];
#pragma unroll
  for (int hh = 0; hh < 8; hh++) acc[hh] = 0.0f;
  for (int j = 0; j < 128; j++) {
    float hj = fmaxf(0.0f, t0 * sw1[2*j] + t1 * sw1[2*j+1] + sb1[j]);
#pragma unroll
    for (int hh = 0; hh < 8; hh++) acc[hh] += hj * sw2[hh*128 + j];
  }
#pragma unroll
  for (int hh = 0; hh < 8; hh++)
    tab[p*8 + hh] = 16.0f / (1.0f + __expf(-acc[hh]));
}

// ---------------------------------------------------------------------------
// Kernel 2: fused qkv linears with residual.
// out[m][half*128+j] = x3[m][half*128+j] + sum_k x3[m][half*128+k]*W[j][k] + b[j]
// x3[m][ch] = x[(b*256+ch)*1024 + n], m = b*1024+n.
// grid (MTOT/64, 6): blockIdx.y = op*2+half, op in {q,k,v}.
// ---------------------------------------------------------------------------
struct QkvPtrs {
  const float* W[6];
  const float* Bv[6];
  float* out[3];
};

__global__ __launch_bounds__(256) void qkv_kernel(const float* __restrict__ x,
                                                  QkvPtrs ptrs) {
  __shared__ float xs[64][33];      // xs[r][kk]
  __shared__ float wt[32 * 132];    // wt[kk*132 + j]  (W transposed tile)
  int t  = threadIdx.x;
  int tx = t & 15;        // col group: cols 8*tx..8*tx+7
  int ty = t >> 4;        // row group: rows 4*ty..4*ty+3
  int which = blockIdx.y;
  int op = which >> 1, half = which & 1;
  const float* W    = ptrs.W[which];
  const float* bias = ptrs.Bv[which];
  float* out = ptrs.out[op];
  int m0 = blockIdx.x * 64;
  int b  = m0 >> 10;
  int n0 = m0 & 1023;
  const float* xbase = x + (size_t)(b*NCH + half*128) * NPOSN + n0; // [k*1024 + r]

  float acc[4][8];
#pragma unroll
  for (int i = 0; i < 4; i++)
#pragma unroll
    for (int j = 0; j < 8; j++) acc[i][j] = 0.0f;

  for (int kc = 0; kc < 4; kc++) {
    // stage x tile (64 rows x 32 k), coalesced over r
#pragma unroll
    for (int i = 0; i < 8; i++) {
      int idx = t + 256*i;
      int kk = idx >> 6, r = idx & 63;
      xs[r][kk] = xbase[(size_t)(kc*32 + kk) * NPOSN + r];
    }
    // stage W tile transposed (coalesced over k)
#pragma unroll
    for (int i = 0; i < 16; i++) {
      int idx = t + 256*i;
      int j = idx >> 5, kk = idx & 31;
      wt[kk*132 + j] = W[j*128 + kc*32 + kk];
    }
    __syncthreads();
#pragma unroll 4
    for (int kk = 0; kk < 32; kk++) {
      float xr[4];
#pragma unroll
      for (int i = 0; i < 4; i++) xr[i] = xs[4*ty + i][kk];
      float4 w0 = *(const float4*)&wt[kk*132 + 8*tx];
      float4 w1 = *(const float4*)&wt[kk*132 + 8*tx + 4];
      float wv[8] = {w0.x, w0.y, w0.z, w0.w, w1.x, w1.y, w1.z, w1.w};
#pragma unroll
      for (int i = 0; i < 4; i++)
#pragma unroll
        for (int j = 0; j < 8; j++)
          acc[i][j] = fmaf(xr[i], wv[j], acc[i][j]);
    }
    __syncthreads();
  }

  // epilogue: += residual + bias, coalesced float4 stores, layout [m][256]
  float bv[8];
#pragma unroll
  for (int j = 0; j < 8; j++) bv[j] = bias[8*tx + j];
#pragma unroll
  for (int i = 0; i < 4; i++) {
    int r = 4*ty + i;
    float v[8];
#pragma unroll
    for (int j = 0; j < 8; j++)
      v[j] = acc[i][j] + bv[j] + xbase[(size_t)(8*tx + j) * NPOSN + r];
    float* dst = out + (size_t)(m0 + r) * NCH + half*128 + 8*tx;
    float4 o0 = {v[0], v[1], v[2], v[3]};
    float4 o1 = {v[4], v[5], v[6], v[7]};
    *(float4*)dst       = o0;
    *(float4*)(dst + 4) = o1;
  }
}

// ---------------------------------------------------------------------------
// Kernel 3: flash attention with cosine-normalized q,k + rel-pos bias.
// grid (16 q-tiles, 8 heads, 16 batch), 256 threads.
// Thread t: r = t&63 (q row in tile), g = t>>6 (score cols 16g..16g+15,
// O dims 8g..8g+7).
// ---------------------------------------------------------------------------
__global__ __launch_bounds__(256) void attn_kernel(
    const float* __restrict__ qv, const float* __restrict__ kv,
    const float* __restrict__ vv, const float* __restrict__ tab,
    const float* __restrict__ logit_scale, float* __restrict__ ao) {
  __shared__ float qs[64][36];
  __shared__ float ks[64][36];
  __shared__ float vs[64][36];
  __shared__ float st[64 * 65];
  __shared__ float mx[4][64];
  __shared__ float sm[4][64];
  __shared__ float rowm[64];
  __shared__ float rowl[64];

  int t = threadIdx.x;
  int qt = blockIdx.x, head = blockIdx.y, b = blockIdx.z;
  int n0 = qt * 64;
  float scale = __expf(fminf(logit_scale[head], 4.6051701859880914f)); // ln(100)

  // ---- load + normalize q tile (norm via 4-lane shuffle reduce) ----
  {
    int r = t >> 2, d8 = (t & 3) * 8;
    const float* src = qv + (size_t)(b*NPOSN + n0 + r) * NCH + head*32 + d8;
    float4 a0 = *(const float4*)src;
    float4 a1 = *(const float4*)(src + 4);
    float ss = a0.x*a0.x + a0.y*a0.y + a0.z*a0.z + a0.w*a0.w
             + a1.x*a1.x + a1.y*a1.y + a1.z*a1.z + a1.w*a1.w;
    ss += __shfl_xor(ss, 1, 64);
    ss += __shfl_xor(ss, 2, 64);
    float rn = scale / fmaxf(sqrtf(ss), 1e-12f);
    a0.x *= rn; a0.y *= rn; a0.z *= rn; a0.w *= rn;
    a1.x *= rn; a1.y *= rn; a1.z *= rn; a1.w *= rn;
    *(float4*)&qs[r][d8]     = a0;
    *(float4*)&qs[r][d8 + 4] = a1;
  }
  if (t < 64) { rowm[t] = -INFINITY; rowl[t] = 0.0f; }
  __syncthreads();

  int r = t & 63;
  int g = t >> 6;
  int c0 = g * 16;
  int d0 = g * 8;
  int rg = n0 + r;
  int ih = rg >> 5, iw = rg & 31;

  // q row into registers (once per block)
  float4 qr4[8];
#pragma unroll
  for (int d4 = 0; d4 < 8; d4++) qr4[d4] = *(const float4*)&qs[r][4*d4];

  float o[8];
#pragma unroll
  for (int j = 0; j < 8; j++) o[j] = 0.0f;

  for (int kt = 0; kt < 16; kt++) {
    // ---- load k (normalized) and v tiles ----
    {
      int rr = t >> 2, d8 = (t & 3) * 8;
      const float* ksrc = kv + (size_t)(b*NPOSN + kt*64 + rr) * NCH + head*32 + d8;
      const float* vsrc = vv + (size_t)(b*NPOSN + kt*64 + rr) * NCH + head*32 + d8;
      float4 k0 = *(const float4*)ksrc;
      float4 k1 = *(const float4*)(ksrc + 4);
      float ss = k0.x*k0.x + k0.y*k0.y + k0.z*k0.z + k0.w*k0.w
               + k1.x*k1.x + k1.y*k1.y + k1.z*k1.z + k1.w*k1.w;
      ss += __shfl_xor(ss, 1, 64);
      ss += __shfl_xor(ss, 2, 64);
      float rn = 1.0f / fmaxf(sqrtf(ss), 1e-12f);
      k0.x *= rn; k0.y *= rn; k0.z *= rn; k0.w *= rn;
      k1.x *= rn; k1.y *= rn; k1.z *= rn; k1.w *= rn;
      *(float4*)&ks[rr][d8]     = k0;
      *(float4*)&ks[rr][d8 + 4] = k1;
      float4 v0 = *(const float4*)vsrc;
      float4 v1 = *(const float4*)(vsrc + 4);
      *(float4*)&vs[rr][d8]     = v0;
      *(float4*)&vs[rr][d8 + 4] = v1;
    }
    __syncthreads();

    // ---- scores: s[cc] = q_r . k_c * (scale folded) + bias ----
    float s[16];
    float lmax = -INFINITY;
#pragma unroll
    for (int cc = 0; cc < 16; cc++) {
      int c = c0 + cc;
      const float4* krow = (const float4*)&ks[c][0];
      float av = 0.0f;
#pragma unroll
      for (int d4 = 0; d4 < 8; d4++) {
        float4 kk4 = krow[d4];
        av += qr4[d4].x*kk4.x + qr4[d4].y*kk4.y
            + qr4[d4].z*kk4.z + qr4[d4].w*kk4.w;
      }
      int cg = kt*64 + c;
      int jh = cg >> 5, jw = cg & 31;
      int idx = (ih - jh + 31) * 63 + (iw - jw + 31);
      av += tab[idx*8 + head];
      s[cc] = av;
      lmax = fmaxf(lmax, av);
    }
    mx[g][r] = lmax;
    __syncthreads();

    // ---- online softmax update ----
    float old_m = rowm[r];
    float new_m = fmaxf(old_m,
                  fmaxf(fmaxf(mx[0][r], mx[1][r]), fmaxf(mx[2][r], mx[3][r])));
    float alpha = __expf(old_m - new_m);
    float lsum = 0.0f;
#pragma unroll
    for (int cc = 0; cc < 16; cc++) {
      float p = __expf(s[cc] - new_m);
      st[r*65 + c0 + cc] = p;
      lsum += p;
    }
    sm[g][r] = lsum;
    __syncthreads();
    if (g == 0) {
      rowm[r] = new_m;
      rowl[r] = rowl[r]*alpha + sm[0][r] + sm[1][r] + sm[2][r] + sm[3][r];
    }

    // ---- PV accumulate: O[r][d0..d0+7] ----
#pragma unroll
    for (int j = 0; j < 8; j++) o[j] *= alpha;
#pragma unroll 8
    for (int c = 0; c < 64; c++) {
      float p = st[r*65 + c];
      float4 v0 = *(const float4*)&vs[c][d0];
      float4 v1 = *(const float4*)&vs[c][d0 + 4];
      o[0] += p*v0.x; o[1] += p*v0.y; o[2] += p*v0.z; o[3] += p*v0.w;
      o[4] += p*v1.x; o[5] += p*v1.y; o[6] += p*v1.z; o[7] += p*v1.w;
    }
    __syncthreads();
  }

  // ---- epilogue: divide by softmax denom, store [m][256] ----
  float linv = 1.0f / rowl[r];
  float4 out0 = {o[0]*linv, o[1]*linv, o[2]*linv, o[3]*linv};
  float4 out1 = {o[4]*linv, o[5]*linv, o[6]*linv, o[7]*linv};
  float* dst = ao + (size_t)(b*NPOSN + n0 + r) * NCH + head*32 + d0;
  *(float4*)dst       = out0;
  *(float4*)(dst + 4) = out1;
}

// ---------------------------------------------------------------------------
// Kernel 4: output projection (no residual), writes [b][ch][n] layout via
// LDS transpose so global stores are coalesced.
// grid (MTOT/64, 2).
// ---------------------------------------------------------------------------
__global__ __launch_bounds__(256) void proj_kernel(
    const float* __restrict__ ain, const float* __restrict__ W1,
    const float* __restrict__ B1, const float* __restrict__ W2,
    const float* __restrict__ B2, float* __restrict__ out) {
  __shared__ float xs[64][33];
  __shared__ float wt[32 * 132];
  __shared__ float yt[128 * 65];
  int t  = threadIdx.x;
  int tx = t & 15, ty = t >> 4;
  int half = blockIdx.y;
  const float* W  = half ? W2 : W1;
  const float* Bs = half ? B2 : B1;
  int m0 = blockIdx.x * 64;
  int b  = m0 >> 10;
  int n0 = m0 & 1023;

  float acc[4][8];
#pragma unroll
  for (int i = 0; i < 4; i++)
#pragma unroll
    for (int j = 0; j < 8; j++) acc[i][j] = 0.0f;

  for (int kc = 0; kc < 4; kc++) {
#pragma unroll
    for (int i = 0; i < 8; i++) {
      int idx = t + 256*i;
      int r = idx >> 5, kk = idx & 31;
      xs[r][kk] = ain[(size_t)(m0 + r) * NCH + half*128 + kc*32 + kk];
    }
#pragma unroll
    for (int i = 0; i < 16; i++) {
      int idx = t + 256*i;
      int j = idx >> 5, kk = idx & 31;
      wt[kk*132 + j] = W[j*128 + kc*32 + kk];
    }
    __syncthreads();
#pragma unroll 4
    for (int kk = 0; kk < 32; kk++) {
      float xr[4];
#pragma unroll
      for (int i = 0; i < 4; i++) xr[i] = xs[4*ty + i][kk];
      float4 w0 = *(const float4*)&wt[kk*132 + 8*tx];
      float4 w1 = *(const float4*)&wt[kk*132 + 8*tx + 4];
      float wv[8] = {w0.x, w0.y, w0.z, w0.w, w1.x, w1.y, w1.z, w1.w};
#pragma unroll
      for (int i = 0; i < 4; i++)
#pragma unroll
        for (int j = 0; j < 8; j++)
          acc[i][j] = fmaf(xr[i], wv[j], acc[i][j]);
    }
    __syncthreads();
  }

  // transpose through LDS for coalesced [ch][n] stores
#pragma unroll
  for (int i = 0; i < 4; i++)
#pragma unroll
    for (int j = 0; j < 8; j++)
      yt[(8*tx + j)*65 + 4*ty + i] = acc[i][j] + Bs[8*tx + j];
  __syncthreads();
  float* obase = out + (size_t)(b*NCH + half*128) * NPOSN + n0;
#pragma unroll
  for (int i = 0; i < 32; i++) {
    int idx = t + 256*i;
    int ch = idx >> 6, r = idx & 63;
    obase[(size_t)ch * NPOSN + r] = yt[ch*65 + r];
  }
}

// ---------------------------------------------------------------------------
extern "C" void kernel_launch(void* const* d_in, const int* in_sizes, int n_in,
                              void* d_out, int out_size, void* d_ws, size_t ws_size,
                              hipStream_t stream) {
  (void)in_sizes; (void)n_in; (void)out_size; (void)ws_size;
  const float* x = (const float*)d_in[0];

  float* ws = (float*)d_ws;
  const size_t SZ = (size_t)MTOT * NCH;  // 4,194,304 floats
  float* qb  = ws;
  float* kb  = ws + SZ;
  float* vb  = ws + 2*SZ;
  float* ao  = ws + 3*SZ;
  float* tab = ws + 4*SZ;               // 3969*8 floats

  // bias table MLP
  bias_mlp_kernel<<<16, 256, 0, stream>>>(
      (const float*)d_in[18], (const float*)d_in[19], (const float*)d_in[20], tab);

  // qkv linears (+ residual)
  QkvPtrs ptrs;
  for (int op = 0; op < 3; op++)
    for (int half = 0; half < 2; half++) {
      ptrs.W[op*2 + half]  = (const float*)d_in[1 + op*4 + half*2];
      ptrs.Bv[op*2 + half] = (const float*)d_in[2 + op*4 + half*2];
    }
  ptrs.out[0] = qb; ptrs.out[1] = kb; ptrs.out[2] = vb;
  qkv_kernel<<<dim3(MTOT/64, 6), 256, 0, stream>>>(x, ptrs);

  // flash attention
  attn_kernel<<<dim3(16, 8, 16), 256, 0, stream>>>(
      qb, kb, vb, tab, (const float*)d_in[17], ao);

  // output projection
  proj_kernel<<<dim3(MTOT/64, 2), 256, 0, stream>>>(
      ao, (const float*)d_in[13], (const float*)d_in[14],
      (const float*)d_in[15], (const float*)d_in[16], (float*)d_out);
}

// Round 3
// 228.716 us; speedup vs baseline: 2.9891x; 2.9891x over previous
//
#include <hip/hip_runtime.h>
#include <cmath>

// ---------------------------------------------------------------------------
// SwinV2-style window attention, f16-MFMA implementation.
// b=16, N=1024 (32x32), c=256, 8 heads x 32 dim, cosine attn + rel-pos-bias MLP.
//
// Pipeline:
//  prep_w   : W (fp32) -> f16, with +Identity folded in for the 6 qkv mats
//             (residual x + x@W^T == x@(W^T+I)); biases packed to ws.
//  bias_mlp : 63x63 rel-pos table through the 2->128->8 MLP, 16*sigmoid,
//             stored [head][3969] for coalesced per-head staging.
//  qkv_mfma : fused 6 linears via MFMA; epilogue normalizes q,k per head
//             (q also scaled by exp(min(logit_scale,ln100))) and stores
//             q,k as [b][h][n][32] f16, v TRANSPOSED as [b][h][d][n] f16.
//  attn_mfma: flash attention, 64-row q-tiles x 16 k-tiles of 64.
//             Scores computed TRANSPOSED (S' = K*Q^T) so each lane owns 4
//             consecutive keys -> P~ goes to LDS with 4x ds_write_b64.
//             Softmax state in registers (row = lane&15, replicated/quad).
//             Bias: only 3*63=189 table entries per (q-tile,k-tile) -> LDS.
//  proj_mfma: 2 linears via MFMA; LDS transpose for coalesced [b][c][n] out.
//
// R2->R3 fix: qkv v-transpose store loop was i<8 (col only reached 64 of 128
// -> heads 2,3,6,7 of V left 0xAA-poisoned). Now i<16: 4096 items cover
// 128 cols x 32 row-pairs.
// ---------------------------------------------------------------------------

typedef _Float16 half_t;
typedef __attribute__((ext_vector_type(4))) _Float16 half4;
typedef __attribute__((ext_vector_type(8))) _Float16 half8;
typedef __attribute__((ext_vector_type(4))) float float4v;

static __device__ __forceinline__ float4v mfma16(half8 a, half8 b, float4v c) {
  return __builtin_amdgcn_mfma_f32_16x16x32_f16(a, b, c, 0, 0, 0);
}

struct PtrArr8 { const float* p[8]; };

// ---------------------------------------------------------------------------
// prep_w: fp32 weights -> f16 (+I for qkv), pack biases.
// grid (16, 8) x 256. matrix y: 0..5 = q1,q2,k1,k2,v1,v2 ; 6,7 = proj1,proj2
// ---------------------------------------------------------------------------
__global__ __launch_bounds__(256) void prep_w(PtrArr8 wsrc, PtrArr8 bsrc,
                                              half_t* __restrict__ wf,
                                              float* __restrict__ bws) {
  int y = blockIdx.y;
  const float* src = nullptr;
  const float* bs = nullptr;
#pragma unroll
  for (int i = 0; i < 8; i++)
    if (i == y) { src = wsrc.p[i]; bs = bsrc.p[i]; }
  int i0 = (blockIdx.x * 256 + threadIdx.x) * 4;
  float4 w = *(const float4*)(src + i0);
  int j = i0 >> 7, k = i0 & 127;
  float id0 = 0.f, id1 = 0.f, id2 = 0.f, id3 = 0.f;
  if (y < 6) {
    if (j == k)     id0 = 1.0f;
    if (j == k + 1) id1 = 1.0f;
    if (j == k + 2) id2 = 1.0f;
    if (j == k + 3) id3 = 1.0f;
  }
  half4 h;
  h[0] = (half_t)(w.x + id0);
  h[1] = (half_t)(w.y + id1);
  h[2] = (half_t)(w.z + id2);
  h[3] = (half_t)(w.w + id3);
  *(half4*)(wf + y * 16384 + i0) = h;
  if (blockIdx.x == 0 && threadIdx.x < 128)
    bws[y * 128 + threadIdx.x] = bs[threadIdx.x];
}

// ---------------------------------------------------------------------------
// bias_mlp: tabh[h][p] = 16*sigmoid(mlp(...)), p over 63x63 grid.
// ---------------------------------------------------------------------------
__global__ __launch_bounds__(256) void bias_mlp(const float* __restrict__ w1,
                                                const float* __restrict__ b1,
                                                const float* __restrict__ w2,
                                                float* __restrict__ tabh) {
  __shared__ float sw1[256];
  __shared__ float sb1[128];
  __shared__ float sw2[1024];
  int t = threadIdx.x;
  sw1[t] = w1[t];
  if (t < 128) sb1[t] = b1[t];
  for (int i = t; i < 1024; i += 256) sw2[i] = w2[i];
  __syncthreads();
  int p = blockIdx.x * 256 + t;
  if (p >= 3969) return;
  int ph = p / 63, pw = p % 63;
  float t0 = (float)(ph - 31) * (3.2f / 31.0f);
  float t1 = (float)(pw - 31) * (3.2f / 31.0f);
  t0 = copysignf(1.0f - __expf(-fabsf(t0)), t0);
  t1 = copysignf(1.0f - __expf(-fabsf(t1)), t1);
  float acc[8];
#pragma unroll
  for (int hh = 0; hh < 8; hh++) acc[hh] = 0.0f;
  for (int j = 0; j < 128; j++) {
    float hj = fmaxf(0.0f, t0 * sw1[2 * j] + t1 * sw1[2 * j + 1] + sb1[j]);
#pragma unroll
    for (int hh = 0; hh < 8; hh++) acc[hh] += hj * sw2[hh * 128 + j];
  }
#pragma unroll
  for (int hh = 0; hh < 8; hh++)
    tabh[hh * 3969 + p] = 16.0f / (1.0f + __expf(-acc[hh]));
}

// ---------------------------------------------------------------------------
// qkv_mfma: 6 fused linears (residual folded into W), per-head q/k norm.
// grid 256 x 256thr. Block = 64 rows (m = b*1024 + n). Wave wv owns 16 rows.
// ---------------------------------------------------------------------------
__global__ __launch_bounds__(256) void qkv_mfma(
    const float* __restrict__ x, const half_t* __restrict__ wf,
    const float* __restrict__ lscale, const float* __restrict__ bws,
    half_t* __restrict__ qf, half_t* __restrict__ kf,
    half_t* __restrict__ vf) {
  __shared__ half_t yt[128 * 68];  // v transpose buffer [col][row]
  int t = threadIdx.x;
  int lane = t & 63, wv = t >> 6, l = lane & 15, quad = lane >> 4;
  int m0 = blockIdx.x * 64;
  int b = m0 >> 10, n0 = m0 & 1023;

  // A fragments: x3 rows (wave's 16 rows), k = channels. x is [b][ch][n].
  half8 afr[8];  // [half*4 + ks]
  {
    const float* xb = x + (size_t)b * 256 * 1024 + n0 + wv * 16 + l;
#pragma unroll
    for (int hf = 0; hf < 2; hf++)
#pragma unroll
      for (int ks = 0; ks < 4; ks++) {
        int kbase = hf * 128 + ks * 32 + quad * 8;
        half8 a;
#pragma unroll
        for (int j = 0; j < 8; j++)
          a[j] = (half_t)xb[(size_t)(kbase + j) * 1024];
        afr[hf * 4 + ks] = a;
      }
  }

#pragma unroll
  for (int combo = 0; combo < 6; combo++) {
    int op = combo >> 1, hf = combo & 1;
    const half_t* wl = wf + combo * 16384 + l * 128 + quad * 8;
    float4v acc[8];
#pragma unroll
    for (int ng = 0; ng < 8; ng++) {
      float4v c = {0.f, 0.f, 0.f, 0.f};
#pragma unroll
      for (int ks = 0; ks < 4; ks++) {
        half8 bfrag = *(const half8*)(wl + ng * 2048 + ks * 32);
        c = mfma16(afr[hf * 4 + ks], bfrag, c);
      }
      acc[ng] = c;
    }
    // bias
#pragma unroll
    for (int ng = 0; ng < 8; ng++) {
      float bb = bws[combo * 128 + ng * 16 + l];
#pragma unroll
      for (int r2 = 0; r2 < 4; r2++) acc[ng][r2] += bb;
    }
    if (op < 2) {
      // normalize per head (cols 32hg..32hg+31 = frags 2hg,2hg+1)
#pragma unroll
      for (int hg = 0; hg < 4; hg++) {
        float sc = 1.0f;
        if (op == 0)
          sc = __expf(fminf(lscale[hf * 4 + hg], 4.6051702f));
#pragma unroll
        for (int r2 = 0; r2 < 4; r2++) {
          float ss = acc[2 * hg][r2] * acc[2 * hg][r2] +
                     acc[2 * hg + 1][r2] * acc[2 * hg + 1][r2];
          ss += __shfl_xor(ss, 1, 64);
          ss += __shfl_xor(ss, 2, 64);
          ss += __shfl_xor(ss, 4, 64);
          ss += __shfl_xor(ss, 8, 64);
          float rn = sc / fmaxf(sqrtf(ss), 1e-12f);
          acc[2 * hg][r2] *= rn;
          acc[2 * hg + 1][r2] *= rn;
        }
      }
      half_t* dst = (op == 0) ? qf : kf;
#pragma unroll
      for (int ng = 0; ng < 8; ng++) {
        int head = hf * 4 + (ng >> 1);
        int d = (ng & 1) * 16 + l;
        size_t base =
            (((size_t)b * 8 + head) * 1024 + n0 + wv * 16 + quad * 4) * 32 + d;
#pragma unroll
        for (int r2 = 0; r2 < 4; r2++)
          dst[base + (size_t)r2 * 32] = (half_t)acc[ng][r2];
      }
    } else {
      // v: LDS transpose -> coalesced store to [b][h][d][n]
#pragma unroll
      for (int ng = 0; ng < 8; ng++) {
        int col = ng * 16 + l;
        half4 hv;
#pragma unroll
        for (int r2 = 0; r2 < 4; r2++) hv[r2] = (half_t)acc[ng][r2];
        *(half4*)(yt + col * 68 + wv * 16 + quad * 4) = hv;
      }
      __syncthreads();
#pragma unroll
      for (int i = 0; i < 16; i++) {   // FIX: 4096 items = 128 cols x 32 row-pairs
        int idx = t + 256 * i;
        int col = idx >> 5, rp = idx & 31;
        unsigned int val = *(const unsigned int*)(yt + col * 68 + rp * 2);
        int head = hf * 4 + (col >> 5);
        int d = col & 31;
        *(unsigned int*)((char*)vf +
                         (((((size_t)b * 8 + head) * 32 + d) * 1024) + n0 +
                          rp * 2) * 2) = val;
      }
      __syncthreads();
    }
  }
}

// ---------------------------------------------------------------------------
// attn_mfma: flash attention. grid (16 qtiles, 8 heads, 16 batch) x 256.
// Wave wv owns 16 q-rows. Scores computed transposed: S' = K * Q^T.
// ---------------------------------------------------------------------------
__global__ __launch_bounds__(256) void attn_mfma(
    const half_t* __restrict__ qf, const half_t* __restrict__ kf,
    const half_t* __restrict__ vf, const float* __restrict__ tabh,
    half_t* __restrict__ ao) {
  __shared__ half_t kb[64 * 40];      // k tile [key][dim], stride 40
  __shared__ half_t vt[32 * 72];      // v tile [dim][key], stride 72
  __shared__ half_t pa[4 * 16 * 72];  // P~ per wave [qrow][key], stride 72
  __shared__ float sbias[192];        // 3 x 63 rel-pos bias entries

  int t = threadIdx.x;
  int lane = t & 63, wv = t >> 6, l = lane & 15, quad = lane >> 4;
  int qt = blockIdx.x, h = blockIdx.y, b = blockIdx.z;
  int n0 = qt * 64;
  size_t bh = (size_t)b * 8 + h;

  // Q fragment (B operand): lane n=l -> q row, k = quad*8+j
  half8 qfr =
      *(const half8*)(qf + (bh * 1024 + n0 + wv * 16 + l) * 32 + quad * 8);

  int qrow_loc = wv * 16 + l;
  int iwq = qrow_loc & 31;
  int ihl = qrow_loc >> 5;

  float run_m = -1e30f, run_l = 0.0f;
  float4v o0 = {0.f, 0.f, 0.f, 0.f}, o1 = {0.f, 0.f, 0.f, 0.f};
  half_t* paw = pa + wv * 16 * 72;

  for (int kt = 0; kt < 16; kt++) {
    __syncthreads();
    {
      int key = t >> 2, dg = t & 3;
      half8 kd =
          *(const half8*)(kf + (bh * 1024 + kt * 64 + key) * 32 + dg * 8);
      *(half8*)(kb + key * 40 + dg * 8) = kd;
      int vd = t >> 3, kg = t & 7;
      half8 vdv =
          *(const half8*)(vf + (bh * 32 + vd) * 1024 + kt * 64 + kg * 8);
      *(half8*)(vt + vd * 72 + kg * 8) = vdv;
      if (t < 189) {
        int r3 = (t >= 126) ? 2 : ((t >= 63) ? 1 : 0);
        int pw = t - r3 * 63;
        int dih = 2 * (qt - kt) + 30 + r3;
        sbias[t] = tabh[h * 3969 + dih * 63 + pw];
      }
    }
    __syncthreads();

    // scores transposed: S'[key][qrow]; lane: qrow=l, keys nt*16+quad*4+r2
    float4v s[4];
#pragma unroll
    for (int nt = 0; nt < 4; nt++) {
      half8 kfr = *(const half8*)(kb + (nt * 16 + l) * 40 + quad * 8);
      float4v z = {0.f, 0.f, 0.f, 0.f};
      s[nt] = mfma16(kfr, qfr, z);
    }
    // bias add + local max
    float lmax = -1e30f;
#pragma unroll
    for (int nt = 0; nt < 4; nt++) {
      int dih_off = ihl - (nt >> 1) + 1;
      int base = dih_off * 63 + iwq + 31 - ((nt & 1) * 16 + 4 * quad);
#pragma unroll
      for (int r2 = 0; r2 < 4; r2++) {
        float v = s[nt][r2] + sbias[base - r2];
        s[nt][r2] = v;
        lmax = fmaxf(lmax, v);
      }
    }
    lmax = fmaxf(lmax, __shfl_xor(lmax, 16, 64));
    lmax = fmaxf(lmax, __shfl_xor(lmax, 32, 64));
    float new_m = fmaxf(run_m, lmax);
    float alpha = __expf(run_m - new_m);
    float lsum = 0.0f;
#pragma unroll
    for (int nt = 0; nt < 4; nt++) {
      half4 ph;
#pragma unroll
      for (int r2 = 0; r2 < 4; r2++) {
        float p = __expf(s[nt][r2] - new_m);
        lsum += p;
        ph[r2] = (half_t)p;
      }
      *(half4*)(paw + l * 72 + nt * 16 + quad * 4) = ph;
    }
    lsum += __shfl_xor(lsum, 16, 64);
    lsum += __shfl_xor(lsum, 32, 64);
    run_l = run_l * alpha + lsum;
    run_m = new_m;
    // rescale O rows by alpha (O rows = 4*quad+r2, alpha held at l==row)
#pragma unroll
    for (int r2 = 0; r2 < 4; r2++) {
      float ar = __shfl(alpha, 20 * quad + r2, 64);
      o0[r2] *= ar;
      o1[r2] *= ar;
    }
    // PV: O[qrow][dim] += P~ * V
#pragma unroll
    for (int ks = 0; ks < 2; ks++) {
      half8 pfr = *(const half8*)(paw + l * 72 + ks * 32 + quad * 8);
      half8 v0f = *(const half8*)(vt + l * 72 + ks * 32 + quad * 8);
      half8 v1f = *(const half8*)(vt + (16 + l) * 72 + ks * 32 + quad * 8);
      o0 = mfma16(pfr, v0f, o0);
      o1 = mfma16(pfr, v1f, o1);
    }
  }

  // epilogue: divide by softmax denom, store ao [m][256] f16
  float rli = 1.0f / run_l;
#pragma unroll
  for (int r2 = 0; r2 < 4; r2++) {
    float linv = __shfl(rli, 20 * quad + r2, 64);
    size_t rowaddr =
        ((size_t)b * 1024 + n0 + wv * 16 + quad * 4 + r2) * 256 + h * 32;
    ao[rowaddr + l] = (half_t)(o0[r2] * linv);
    ao[rowaddr + 16 + l] = (half_t)(o1[r2] * linv);
  }
}

// ---------------------------------------------------------------------------
// proj_mfma: output projection, fp32 out in [b][ch][n] via LDS transpose.
// grid 256 x 256.
// ---------------------------------------------------------------------------
__global__ __launch_bounds__(256) void proj_mfma(
    const half_t* __restrict__ ao, const half_t* __restrict__ wp,
    const float* __restrict__ bws, float* __restrict__ out) {
  __shared__ float yt[128 * 68];
  int t = threadIdx.x;
  int lane = t & 63, wv = t >> 6, l = lane & 15, quad = lane >> 4;
  int m0 = blockIdx.x * 64;
  int b = m0 >> 10, n0 = m0 & 1023;

#pragma unroll
  for (int hf = 0; hf < 2; hf++) {
    half8 afr[4];
    const half_t* ab =
        ao + ((size_t)m0 + wv * 16 + l) * 256 + hf * 128 + quad * 8;
#pragma unroll
    for (int ks = 0; ks < 4; ks++) afr[ks] = *(const half8*)(ab + ks * 32);
    const half_t* wl = wp + hf * 16384 + l * 128 + quad * 8;
#pragma unroll
    for (int ng = 0; ng < 8; ng++) {
      float4v c = {0.f, 0.f, 0.f, 0.f};
#pragma unroll
      for (int ks = 0; ks < 4; ks++)
        c = mfma16(afr[ks], *(const half8*)(wl + ng * 2048 + ks * 32), c);
      float bb = bws[(6 + hf) * 128 + ng * 16 + l];
#pragma unroll
      for (int r2 = 0; r2 < 4; r2++) c[r2] += bb;
      // write transposed: [col][row], float4 covers rows 4quad..+3
      *(float4v*)(yt + (ng * 16 + l) * 68 + wv * 16 + quad * 4) = c;
    }
    __syncthreads();
#pragma unroll
    for (int i = 0; i < 8; i++) {
      int idx = t + 256 * i;
      int col = idx >> 4, rg = idx & 15;
      float4v vv = *(const float4v*)(yt + col * 68 + rg * 4);
      *(float4v*)(out + ((size_t)b * 256 + hf * 128 + col) * 1024 + n0 +
                  rg * 4) = vv;
    }
    __syncthreads();
  }
}

// ---------------------------------------------------------------------------
extern "C" void kernel_launch(void* const* d_in, const int* in_sizes, int n_in,
                              void* d_out, int out_size, void* d_ws,
                              size_t ws_size, hipStream_t stream) {
  (void)in_sizes; (void)n_in; (void)out_size; (void)ws_size;
  const float* x = (const float*)d_in[0];

  half_t* ws = (half_t*)d_ws;
  half_t* qfp = ws;                    // [16][8][1024][32] f16
  half_t* kfp = ws + 4194304;          // [16][8][1024][32] f16
  half_t* vfp = ws + 8388608;          // [16][8][32][1024] f16 (transposed)
  half_t* aop = ws + 12582912;         // [16384][256] f16
  half_t* wfp = ws + 16777216;         // 8 x 128x128 f16
  float* tabh = (float*)((char*)d_ws + 33816576);  // [8][3969] f32
  float* bws = (float*)((char*)d_ws + 33943584);   // [8][128] f32

  PtrArr8 wsrc, bsrc;
  const int widx[8] = {1, 3, 5, 7, 9, 11, 13, 15};
  for (int i = 0; i < 8; i++) {
    wsrc.p[i] = (const float*)d_in[widx[i]];
    bsrc.p[i] = (const float*)d_in[widx[i] + 1];
  }

  prep_w<<<dim3(16, 8), 256, 0, stream>>>(wsrc, bsrc, wfp, bws);
  bias_mlp<<<16, 256, 0, stream>>>((const float*)d_in[18],
                                   (const float*)d_in[19],
                                   (const float*)d_in[20], tabh);
  qkv_mfma<<<256, 256, 0, stream>>>(x, wfp, (const float*)d_in[17], bws, qfp,
                                    kfp, vfp);
  attn_mfma<<<dim3(16, 8, 16), 256, 0, stream>>>(qfp, kfp, vfp, tabh, aop);
  proj_mfma<<<256, 256, 0, stream>>>(aop, wfp + 6 * 16384, bws,
                                     (float*)d_out);
}

// Round 4
// 209.154 us; speedup vs baseline: 3.2687x; 1.0935x over previous
//
#include <hip/hip_runtime.h>
#include <cmath>

// ---------------------------------------------------------------------------
// SwinV2-style window attention, f16-MFMA implementation.  Round 4.
//
// R3->R4:
//  * attn: one-pass softmax with FIXED max M = scale+16 (scores bounded:
//    |cos|<=1, bias in [0,16]).  P~ = exp2(s*log2e + 14 - M*log2e) keeps f16
//    P~ in normal range (max 2^14).  Removes per-tile max/alpha/bpermute
//    machinery; bias enters as the C-init of the QK MFMA.
//  * attn: register-prefetch of next K/V/bias tile across the barrier.
//  * qkv/proj: hf split across blockIdx.y -> 2x blocks, half serial work.
// ---------------------------------------------------------------------------

typedef _Float16 half_t;
typedef __attribute__((ext_vector_type(4))) _Float16 half4;
typedef __attribute__((ext_vector_type(8))) _Float16 half8;
typedef __attribute__((ext_vector_type(4))) float float4v;

static __device__ __forceinline__ float4v mfma16(half8 a, half8 b, float4v c) {
  return __builtin_amdgcn_mfma_f32_16x16x32_f16(a, b, c, 0, 0, 0);
}

struct PtrArr8 { const float* p[8]; };

// ---------------------------------------------------------------------------
// prep_w: fp32 weights -> f16 (+I for qkv), pack biases.
// grid (16, 8) x 256. matrix y: 0..5 = q1,q2,k1,k2,v1,v2 ; 6,7 = proj1,proj2
// ---------------------------------------------------------------------------
__global__ __launch_bounds__(256) void prep_w(PtrArr8 wsrc, PtrArr8 bsrc,
                                              half_t* __restrict__ wf,
                                              float* __restrict__ bws) {
  int y = blockIdx.y;
  const float* src = nullptr;
  const float* bs = nullptr;
#pragma unroll
  for (int i = 0; i < 8; i++)
    if (i == y) { src = wsrc.p[i]; bs = bsrc.p[i]; }
  int i0 = (blockIdx.x * 256 + threadIdx.x) * 4;
  float4 w = *(const float4*)(src + i0);
  int j = i0 >> 7, k = i0 & 127;
  float id0 = 0.f, id1 = 0.f, id2 = 0.f, id3 = 0.f;
  if (y < 6) {
    if (j == k)     id0 = 1.0f;
    if (j == k + 1) id1 = 1.0f;
    if (j == k + 2) id2 = 1.0f;
    if (j == k + 3) id3 = 1.0f;
  }
  half4 h;
  h[0] = (half_t)(w.x + id0);
  h[1] = (half_t)(w.y + id1);
  h[2] = (half_t)(w.z + id2);
  h[3] = (half_t)(w.w + id3);
  *(half4*)(wf + y * 16384 + i0) = h;
  if (blockIdx.x == 0 && threadIdx.x < 128)
    bws[y * 128 + threadIdx.x] = bs[threadIdx.x];
}

// ---------------------------------------------------------------------------
// bias_mlp: tabh[h][p] = 16*sigmoid(mlp(...)), p over 63x63 grid.
// ---------------------------------------------------------------------------
__global__ __launch_bounds__(256) void bias_mlp(const float* __restrict__ w1,
                                                const float* __restrict__ b1,
                                                const float* __restrict__ w2,
                                                float* __restrict__ tabh) {
  __shared__ float sw1[256];
  __shared__ float sb1[128];
  __shared__ float sw2[1024];
  int t = threadIdx.x;
  sw1[t] = w1[t];
  if (t < 128) sb1[t] = b1[t];
  for (int i = t; i < 1024; i += 256) sw2[i] = w2[i];
  __syncthreads();
  int p = blockIdx.x * 256 + t;
  if (p >= 3969) return;
  int ph = p / 63, pw = p % 63;
  float t0 = (float)(ph - 31) * (3.2f / 31.0f);
  float t1 = (float)(pw - 31) * (3.2f / 31.0f);
  t0 = copysignf(1.0f - __expf(-fabsf(t0)), t0);
  t1 = copysignf(1.0f - __expf(-fabsf(t1)), t1);
  float acc[8];
#pragma unroll
  for (int hh = 0; hh < 8; hh++) acc[hh] = 0.0f;
  for (int j = 0; j < 128; j++) {
    float hj = fmaxf(0.0f, t0 * sw1[2 * j] + t1 * sw1[2 * j + 1] + sb1[j]);
#pragma unroll
    for (int hh = 0; hh < 8; hh++) acc[hh] += hj * sw2[hh * 128 + j];
  }
#pragma unroll
  for (int hh = 0; hh < 8; hh++)
    tabh[hh * 3969 + p] = 16.0f / (1.0f + __expf(-acc[hh]));
}

// ---------------------------------------------------------------------------
// qkv_mfma: 3 fused linears for one half (residual folded into W),
// per-head q/k norm.  grid (256, 2) x 256; blockIdx.y = hf.
// ---------------------------------------------------------------------------
__global__ __launch_bounds__(256) void qkv_mfma(
    const float* __restrict__ x, const half_t* __restrict__ wf,
    const float* __restrict__ lscale, const float* __restrict__ bws,
    half_t* __restrict__ qf, half_t* __restrict__ kf,
    half_t* __restrict__ vf) {
  __shared__ half_t yt[128 * 68];  // v transpose buffer [col][row]
  int t = threadIdx.x;
  int lane = t & 63, wv = t >> 6, l = lane & 15, quad = lane >> 4;
  int hf = blockIdx.y;
  int m0 = blockIdx.x * 64;
  int b = m0 >> 10, n0 = m0 & 1023;

  // A fragments: this half's channels. x is [b][ch][n].
  half8 afr[4];
  {
    const float* xb = x + (size_t)b * 256 * 1024 + n0 + wv * 16 + l;
#pragma unroll
    for (int ks = 0; ks < 4; ks++) {
      int kbase = hf * 128 + ks * 32 + quad * 8;
      half8 a;
#pragma unroll
      for (int j = 0; j < 8; j++)
        a[j] = (half_t)xb[(size_t)(kbase + j) * 1024];
      afr[ks] = a;
    }
  }

#pragma unroll
  for (int op = 0; op < 3; op++) {
    int combo = op * 2 + hf;
    const half_t* wl = wf + combo * 16384 + l * 128 + quad * 8;
    float4v acc[8];
#pragma unroll
    for (int ng = 0; ng < 8; ng++) {
      float4v c = {0.f, 0.f, 0.f, 0.f};
#pragma unroll
      for (int ks = 0; ks < 4; ks++) {
        half8 bfrag = *(const half8*)(wl + ng * 2048 + ks * 32);
        c = mfma16(afr[ks], bfrag, c);
      }
      acc[ng] = c;
    }
    // bias
#pragma unroll
    for (int ng = 0; ng < 8; ng++) {
      float bb = bws[combo * 128 + ng * 16 + l];
#pragma unroll
      for (int r2 = 0; r2 < 4; r2++) acc[ng][r2] += bb;
    }
    if (op < 2) {
      // normalize per head (cols 32hg..32hg+31 = frags 2hg,2hg+1)
#pragma unroll
      for (int hg = 0; hg < 4; hg++) {
        float sc = 1.0f;
        if (op == 0)
          sc = __expf(fminf(lscale[hf * 4 + hg], 4.6051702f));
#pragma unroll
        for (int r2 = 0; r2 < 4; r2++) {
          float ss = acc[2 * hg][r2] * acc[2 * hg][r2] +
                     acc[2 * hg + 1][r2] * acc[2 * hg + 1][r2];
          ss += __shfl_xor(ss, 1, 64);
          ss += __shfl_xor(ss, 2, 64);
          ss += __shfl_xor(ss, 4, 64);
          ss += __shfl_xor(ss, 8, 64);
          float rn = sc / fmaxf(sqrtf(ss), 1e-12f);
          acc[2 * hg][r2] *= rn;
          acc[2 * hg + 1][r2] *= rn;
        }
      }
      half_t* dst = (op == 0) ? qf : kf;
#pragma unroll
      for (int ng = 0; ng < 8; ng++) {
        int head = hf * 4 + (ng >> 1);
        int d = (ng & 1) * 16 + l;
        size_t base =
            (((size_t)b * 8 + head) * 1024 + n0 + wv * 16 + quad * 4) * 32 + d;
#pragma unroll
        for (int r2 = 0; r2 < 4; r2++)
          dst[base + (size_t)r2 * 32] = (half_t)acc[ng][r2];
      }
    } else {
      // v: LDS transpose -> coalesced store to [b][h][d][n]
#pragma unroll
      for (int ng = 0; ng < 8; ng++) {
        int col = ng * 16 + l;
        half4 hv;
#pragma unroll
        for (int r2 = 0; r2 < 4; r2++) hv[r2] = (half_t)acc[ng][r2];
        *(half4*)(yt + col * 68 + wv * 16 + quad * 4) = hv;
      }
      __syncthreads();
#pragma unroll
      for (int i = 0; i < 16; i++) {  // 4096 items = 128 cols x 32 row-pairs
        int idx = t + 256 * i;
        int col = idx >> 5, rp = idx & 31;
        unsigned int val = *(const unsigned int*)(yt + col * 68 + rp * 2);
        int head = hf * 4 + (col >> 5);
        int d = col & 31;
        *(unsigned int*)((char*)vf +
                         (((((size_t)b * 8 + head) * 32 + d) * 1024) + n0 +
                          rp * 2) * 2) = val;
      }
    }
  }
}

// ---------------------------------------------------------------------------
// attn_mfma: flash attention, one-pass fixed-max softmax.
// grid (16 qtiles, 8 heads, 16 batch) x 256.  Wave wv owns 16 q-rows.
// Scores transposed: S' = K * Q^T.  P~ = exp2(s*log2e + 14 - M*log2e),
// M = scale + 16 >= any score (|cos|<=1 * scale + bias<=16); the 2^14
// rescale keeps f16 P~ in normal range (max 16384), denominator cancels it.
// Next K/V/bias tile is register-prefetched across the barrier.
// ---------------------------------------------------------------------------
__global__ __launch_bounds__(256) void attn_mfma(
    const half_t* __restrict__ qf, const half_t* __restrict__ kf,
    const half_t* __restrict__ vf, const float* __restrict__ tabh,
    const float* __restrict__ lscale, half_t* __restrict__ ao) {
  __shared__ half_t kb[64 * 40];      // k tile [key][dim], stride 40
  __shared__ half_t vt[32 * 72];      // v tile [dim][key], stride 72
  __shared__ half_t pa[4 * 16 * 72];  // P~ per wave [qrow][key], stride 72
  __shared__ float sbias[192];        // 3 x 63 rel-pos bias entries

  int t = threadIdx.x;
  int lane = t & 63, wv = t >> 6, l = lane & 15, quad = lane >> 4;
  int qt = blockIdx.x, h = blockIdx.y, b = blockIdx.z;
  int n0 = qt * 64;
  size_t bh = (size_t)b * 8 + h;
  float scale = __expf(fminf(lscale[h], 4.6051702f));
  float c14 = 14.0f - (scale + 16.0f) * 1.44269504f;

  // Q fragment (B operand): lane n=l -> q row, k = quad*8+j
  half8 qfr =
      *(const half8*)(qf + (bh * 1024 + n0 + wv * 16 + l) * 32 + quad * 8);

  int qrow_loc = wv * 16 + l;
  int iwq = qrow_loc & 31;
  int ihl = qrow_loc >> 5;

  float run_l = 0.0f;
  float4v o0 = {0.f, 0.f, 0.f, 0.f}, o1 = {0.f, 0.f, 0.f, 0.f};
  half_t* paw = pa + wv * 16 * 72;

  // staging thread roles
  int key_s = t >> 2, dg_s = t & 3;   // K: 64 keys x 4 dim-groups
  int vd_s = t >> 3, kg_s = t & 7;    // V: 32 dims x 8 key-groups
  int r3 = (t >= 126) ? 2 : ((t >= 63) ? 1 : 0);
  int pw_s = t - r3 * 63;

  // prefetch tile 0
  half8 kreg = *(const half8*)(kf + (bh * 1024 + key_s) * 32 + dg_s * 8);
  half8 vreg = *(const half8*)(vf + (bh * 32 + vd_s) * 1024 + kg_s * 8);
  float breg = 0.0f;
  if (t < 189) breg = tabh[h * 3969 + (2 * qt + 30 + r3) * 63 + pw_s];

  for (int kt = 0; kt < 16; kt++) {
    // commit staged tile to LDS
    *(half8*)(kb + key_s * 40 + dg_s * 8) = kreg;
    *(half8*)(vt + vd_s * 72 + kg_s * 8) = vreg;
    if (t < 189) sbias[t] = breg;
    __syncthreads();
    // issue next-tile global loads (land during compute below)
    if (kt < 15) {
      kreg = *(const half8*)(kf +
                             (bh * 1024 + (kt + 1) * 64 + key_s) * 32 +
                             dg_s * 8);
      vreg = *(const half8*)(vf + (bh * 32 + vd_s) * 1024 + (kt + 1) * 64 +
                             kg_s * 8);
      if (t < 189)
        breg = tabh[h * 3969 + (2 * (qt - kt - 1) + 30 + r3) * 63 + pw_s];
    }

    // scores transposed: S'[key][qrow]; lane: qrow=l, keys nt*16+quad*4+r2.
    // Bias enters as the MFMA C-initializer.
    float4v s[4];
#pragma unroll
    for (int nt = 0; nt < 4; nt++) {
      int base = (ihl - (nt >> 1) + 1) * 63 + iwq + 31 -
                 ((nt & 1) * 16 + 4 * quad);
      float4v c;
      c[0] = sbias[base];
      c[1] = sbias[base - 1];
      c[2] = sbias[base - 2];
      c[3] = sbias[base - 3];
      half8 kfr = *(const half8*)(kb + (nt * 16 + l) * 40 + quad * 8);
      s[nt] = mfma16(kfr, qfr, c);
    }
    // P~ = exp2(s*log2e + c14); accumulate per-lane partial row sum
#pragma unroll
    for (int nt = 0; nt < 4; nt++) {
      half4 ph;
#pragma unroll
      for (int r2 = 0; r2 < 4; r2++) {
        float p = exp2f(fmaf(s[nt][r2], 1.44269504f, c14));
        run_l += p;
        ph[r2] = (half_t)p;
      }
      *(half4*)(paw + l * 72 + nt * 16 + quad * 4) = ph;
    }
    // PV: O[qrow][dim] += P~ * V
#pragma unroll
    for (int ks = 0; ks < 2; ks++) {
      half8 pfr = *(const half8*)(paw + l * 72 + ks * 32 + quad * 8);
      half8 v0f = *(const half8*)(vt + l * 72 + ks * 32 + quad * 8);
      half8 v1f = *(const half8*)(vt + (16 + l) * 72 + ks * 32 + quad * 8);
      o0 = mfma16(pfr, v0f, o0);
      o1 = mfma16(pfr, v1f, o1);
    }
    __syncthreads();
  }

  // full row sum: reduce over quads (lane l, l+16, l+32, l+48)
  run_l += __shfl_xor(run_l, 16, 64);
  run_l += __shfl_xor(run_l, 32, 64);
  float rli = 1.0f / run_l;

  // epilogue: O rows = 4*quad+r2 (dim = l / 16+l); fetch row's 1/l via shfl
#pragma unroll
  for (int r2 = 0; r2 < 4; r2++) {
    float linv = __shfl(rli, 20 * quad + r2, 64);
    size_t rowaddr =
        ((size_t)b * 1024 + n0 + wv * 16 + quad * 4 + r2) * 256 + h * 32;
    ao[rowaddr + l] = (half_t)(o0[r2] * linv);
    ao[rowaddr + 16 + l] = (half_t)(o1[r2] * linv);
  }
}

// ---------------------------------------------------------------------------
// proj_mfma: output projection for one half, fp32 out [b][ch][n] via LDS
// transpose.  grid (256, 2) x 256; blockIdx.y = hf.
// ---------------------------------------------------------------------------
__global__ __launch_bounds__(256) void proj_mfma(
    const half_t* __restrict__ ao, const half_t* __restrict__ wp,
    const float* __restrict__ bws, float* __restrict__ out) {
  __shared__ float yt[128 * 68];
  int t = threadIdx.x;
  int lane = t & 63, wv = t >> 6, l = lane & 15, quad = lane >> 4;
  int hf = blockIdx.y;
  int m0 = blockIdx.x * 64;
  int b = m0 >> 10, n0 = m0 & 1023;

  half8 afr[4];
  const half_t* ab =
      ao + ((size_t)m0 + wv * 16 + l) * 256 + hf * 128 + quad * 8;
#pragma unroll
  for (int ks = 0; ks < 4; ks++) afr[ks] = *(const half8*)(ab + ks * 32);
  const half_t* wl = wp + hf * 16384 + l * 128 + quad * 8;
#pragma unroll
  for (int ng = 0; ng < 8; ng++) {
    float4v c = {0.f, 0.f, 0.f, 0.f};
#pragma unroll
    for (int ks = 0; ks < 4; ks++)
      c = mfma16(afr[ks], *(const half8*)(wl + ng * 2048 + ks * 32), c);
    float bb = bws[(6 + hf) * 128 + ng * 16 + l];
#pragma unroll
    for (int r2 = 0; r2 < 4; r2++) c[r2] += bb;
    // write transposed: [col][row], float4 covers rows 4quad..+3
    *(float4v*)(yt + (ng * 16 + l) * 68 + wv * 16 + quad * 4) = c;
  }
  __syncthreads();
#pragma unroll
  for (int i = 0; i < 8; i++) {
    int idx = t + 256 * i;
    int col = idx >> 4, rg = idx & 15;
    float4v vv = *(const float4v*)(yt + col * 68 + rg * 4);
    *(float4v*)(out + ((size_t)b * 256 + hf * 128 + col) * 1024 + n0 +
                rg * 4) = vv;
  }
}

// ---------------------------------------------------------------------------
extern "C" void kernel_launch(void* const* d_in, const int* in_sizes, int n_in,
                              void* d_out, int out_size, void* d_ws,
                              size_t ws_size, hipStream_t stream) {
  (void)in_sizes; (void)n_in; (void)out_size; (void)ws_size;
  const float* x = (const float*)d_in[0];

  half_t* ws = (half_t*)d_ws;
  half_t* qfp = ws;                    // [16][8][1024][32] f16
  half_t* kfp = ws + 4194304;          // [16][8][1024][32] f16
  half_t* vfp = ws + 8388608;          // [16][8][32][1024] f16 (transposed)
  half_t* aop = ws + 12582912;         // [16384][256] f16
  half_t* wfp = ws + 16777216;         // 8 x 128x128 f16
  float* tabh = (float*)((char*)d_ws + 33816576);  // [8][3969] f32
  float* bws = (float*)((char*)d_ws + 33943584);   // [8][128] f32

  PtrArr8 wsrc, bsrc;
  const int widx[8] = {1, 3, 5, 7, 9, 11, 13, 15};
  for (int i = 0; i < 8; i++) {
    wsrc.p[i] = (const float*)d_in[widx[i]];
    bsrc.p[i] = (const float*)d_in[widx[i] + 1];
  }

  prep_w<<<dim3(16, 8), 256, 0, stream>>>(wsrc, bsrc, wfp, bws);
  bias_mlp<<<16, 256, 0, stream>>>((const float*)d_in[18],
                                   (const float*)d_in[19],
                                   (const float*)d_in[20], tabh);
  qkv_mfma<<<dim3(256, 2), 256, 0, stream>>>(x, wfp, (const float*)d_in[17],
                                             bws, qfp, kfp, vfp);
  attn_mfma<<<dim3(16, 8, 16), 256, 0, stream>>>(
      qfp, kfp, vfp, tabh, (const float*)d_in[17], aop);
  proj_mfma<<<dim3(256, 2), 256, 0, stream>>>(aop, wfp + 6 * 16384, bws,
                                              (float*)d_out);
}

// Round 5
// 193.513 us; speedup vs baseline: 3.5329x; 1.0808x over previous
//
#include <hip/hip_runtime.h>
#include <cmath>

// ---------------------------------------------------------------------------
// SwinV2-style window attention, f16-MFMA implementation.  Round 5.
//
// R4->R5 (qkv/proj memory-pattern fix; attn untouched):
//  * Weight fragments were global gathers at 256 B/lane stride (64 cache
//    lines per instruction, 96 instrs/thread).  Now: W staged to LDS with
//    coalesced half8 loads, fragments read via ds_read_b128 at padded
//    stride 136 halves (2-way banks = free).
//  * q/k epilogue stores were 64 scalar 2 B global stores/thread.  Now:
//    LDS transpose (stride-132 buffer) -> coalesced half8 global stores.
// ---------------------------------------------------------------------------

typedef _Float16 half_t;
typedef __attribute__((ext_vector_type(4))) _Float16 half4;
typedef __attribute__((ext_vector_type(8))) _Float16 half8;
typedef __attribute__((ext_vector_type(4))) float float4v;

static __device__ __forceinline__ float4v mfma16(half8 a, half8 b, float4v c) {
  return __builtin_amdgcn_mfma_f32_16x16x32_f16(a, b, c, 0, 0, 0);
}

struct PtrArr8 { const float* p[8]; };

// ---------------------------------------------------------------------------
// prep_w: fp32 weights -> f16 (+I for qkv), pack biases.
// grid (16, 8) x 256. matrix y: 0..5 = q1,q2,k1,k2,v1,v2 ; 6,7 = proj1,proj2
// ---------------------------------------------------------------------------
__global__ __launch_bounds__(256) void prep_w(PtrArr8 wsrc, PtrArr8 bsrc,
                                              half_t* __restrict__ wf,
                                              float* __restrict__ bws) {
  int y = blockIdx.y;
  const float* src = nullptr;
  const float* bs = nullptr;
#pragma unroll
  for (int i = 0; i < 8; i++)
    if (i == y) { src = wsrc.p[i]; bs = bsrc.p[i]; }
  int i0 = (blockIdx.x * 256 + threadIdx.x) * 4;
  float4 w = *(const float4*)(src + i0);
  int j = i0 >> 7, k = i0 & 127;
  float id0 = 0.f, id1 = 0.f, id2 = 0.f, id3 = 0.f;
  if (y < 6) {
    if (j == k)     id0 = 1.0f;
    if (j == k + 1) id1 = 1.0f;
    if (j == k + 2) id2 = 1.0f;
    if (j == k + 3) id3 = 1.0f;
  }
  half4 h;
  h[0] = (half_t)(w.x + id0);
  h[1] = (half_t)(w.y + id1);
  h[2] = (half_t)(w.z + id2);
  h[3] = (half_t)(w.w + id3);
  *(half4*)(wf + y * 16384 + i0) = h;
  if (blockIdx.x == 0 && threadIdx.x < 128)
    bws[y * 128 + threadIdx.x] = bs[threadIdx.x];
}

// ---------------------------------------------------------------------------
// bias_mlp: tabh[h][p] = 16*sigmoid(mlp(...)), p over 63x63 grid.
// ---------------------------------------------------------------------------
__global__ __launch_bounds__(256) void bias_mlp(const float* __restrict__ w1,
                                                const float* __restrict__ b1,
                                                const float* __restrict__ w2,
                                                float* __restrict__ tabh) {
  __shared__ float sw1[256];
  __shared__ float sb1[128];
  __shared__ float sw2[1024];
  int t = threadIdx.x;
  sw1[t] = w1[t];
  if (t < 128) sb1[t] = b1[t];
  for (int i = t; i < 1024; i += 256) sw2[i] = w2[i];
  __syncthreads();
  int p = blockIdx.x * 256 + t;
  if (p >= 3969) return;
  int ph = p / 63, pw = p % 63;
  float t0 = (float)(ph - 31) * (3.2f / 31.0f);
  float t1 = (float)(pw - 31) * (3.2f / 31.0f);
  t0 = copysignf(1.0f - __expf(-fabsf(t0)), t0);
  t1 = copysignf(1.0f - __expf(-fabsf(t1)), t1);
  float acc[8];
#pragma unroll
  for (int hh = 0; hh < 8; hh++) acc[hh] = 0.0f;
  for (int j = 0; j < 128; j++) {
    float hj = fmaxf(0.0f, t0 * sw1[2 * j] + t1 * sw1[2 * j + 1] + sb1[j]);
#pragma unroll
    for (int hh = 0; hh < 8; hh++) acc[hh] += hj * sw2[hh * 128 + j];
  }
#pragma unroll
  for (int hh = 0; hh < 8; hh++)
    tabh[hh * 3969 + p] = 16.0f / (1.0f + __expf(-acc[hh]));
}

// ---------------------------------------------------------------------------
// qkv_mfma: 3 fused linears for one half (residual folded into W),
// per-head q/k norm.  grid (256, 2) x 256; blockIdx.y = hf.
// W staged in LDS (stride 136); q/k epilogue via LDS transpose (stride 132).
// ---------------------------------------------------------------------------
__global__ __launch_bounds__(256) void qkv_mfma(
    const float* __restrict__ x, const half_t* __restrict__ wf,
    const float* __restrict__ lscale, const float* __restrict__ bws,
    half_t* __restrict__ qf, half_t* __restrict__ kf,
    half_t* __restrict__ vf) {
  __shared__ half_t wb[128 * 136];  // weight tile, padded
  __shared__ half_t tbuf[128 * 68]; // transpose buffer (q/k: 64x132 view)
  int t = threadIdx.x;
  int lane = t & 63, wv = t >> 6, l = lane & 15, quad = lane >> 4;
  int hf = blockIdx.y;
  int m0 = blockIdx.x * 64;
  int b = m0 >> 10, n0 = m0 & 1023;

  // A fragments: this half's channels. x is [b][ch][n].
  half8 afr[4];
  {
    const float* xb = x + (size_t)b * 256 * 1024 + n0 + wv * 16 + l;
#pragma unroll
    for (int ks = 0; ks < 4; ks++) {
      int kbase = hf * 128 + ks * 32 + quad * 8;
      half8 a;
#pragma unroll
      for (int j = 0; j < 8; j++)
        a[j] = (half_t)xb[(size_t)(kbase + j) * 1024];
      afr[ks] = a;
    }
  }

  for (int op = 0; op < 3; op++) {
    int combo = op * 2 + hf;
    // stage W into LDS, coalesced
    __syncthreads();
    {
      const half_t* wg = wf + combo * 16384;
#pragma unroll
      for (int i = 0; i < 8; i++) {
        int flat = (t + 256 * i) * 8;
        int row = flat >> 7, col = flat & 127;
        *(half8*)(wb + row * 136 + col) = *(const half8*)(wg + flat);
      }
    }
    __syncthreads();

    float4v acc[8];
#pragma unroll
    for (int ng = 0; ng < 8; ng++) {
      float4v c = {0.f, 0.f, 0.f, 0.f};
#pragma unroll
      for (int ks = 0; ks < 4; ks++) {
        half8 bfrag =
            *(const half8*)(wb + (ng * 16 + l) * 136 + ks * 32 + quad * 8);
        c = mfma16(afr[ks], bfrag, c);
      }
      acc[ng] = c;
    }
    // bias
#pragma unroll
    for (int ng = 0; ng < 8; ng++) {
      float bb = bws[combo * 128 + ng * 16 + l];
#pragma unroll
      for (int r2 = 0; r2 < 4; r2++) acc[ng][r2] += bb;
    }
    if (op < 2) {
      // normalize per head (cols 32hg..32hg+31 = frags 2hg,2hg+1)
#pragma unroll
      for (int hg = 0; hg < 4; hg++) {
        float sc = 1.0f;
        if (op == 0)
          sc = __expf(fminf(lscale[hf * 4 + hg], 4.6051702f));
#pragma unroll
        for (int r2 = 0; r2 < 4; r2++) {
          float ss = acc[2 * hg][r2] * acc[2 * hg][r2] +
                     acc[2 * hg + 1][r2] * acc[2 * hg + 1][r2];
          ss += __shfl_xor(ss, 1, 64);
          ss += __shfl_xor(ss, 2, 64);
          ss += __shfl_xor(ss, 4, 64);
          ss += __shfl_xor(ss, 8, 64);
          float rn = sc / fmaxf(sqrtf(ss), 1e-12f);
          acc[2 * hg][r2] *= rn;
          acc[2 * hg + 1][r2] *= rn;
        }
      }
      // q/k: row-major LDS transpose -> coalesced half8 stores [b,h,n,32]
#pragma unroll
      for (int ng = 0; ng < 8; ng++)
#pragma unroll
        for (int r2 = 0; r2 < 4; r2++)
          tbuf[(wv * 16 + quad * 4 + r2) * 132 + ng * 16 + l] =
              (half_t)acc[ng][r2];
      __syncthreads();
      half_t* dst = (op == 0) ? qf : kf;
#pragma unroll
      for (int i = 0; i < 4; i++) {
        int idx = t + 256 * i;
        int row = idx >> 4, colc = (idx & 15) * 8;
        half8 vv = *(const half8*)(tbuf + row * 132 + colc);
        int head = hf * 4 + (colc >> 5), d = colc & 31;
        *(half8*)(dst + (((size_t)b * 8 + head) * 1024 + n0 + row) * 32 + d) =
            vv;
      }
    } else {
      // v: col-major LDS transpose -> coalesced dword store to [b][h][d][n]
#pragma unroll
      for (int ng = 0; ng < 8; ng++) {
        int col = ng * 16 + l;
        half4 hv;
#pragma unroll
        for (int r2 = 0; r2 < 4; r2++) hv[r2] = (half_t)acc[ng][r2];
        *(half4*)(tbuf + col * 68 + wv * 16 + quad * 4) = hv;
      }
      __syncthreads();
#pragma unroll
      for (int i = 0; i < 16; i++) {  // 4096 items = 128 cols x 32 row-pairs
        int idx = t + 256 * i;
        int col = idx >> 5, rp = idx & 31;
        unsigned int val = *(const unsigned int*)(tbuf + col * 68 + rp * 2);
        int head = hf * 4 + (col >> 5);
        int d = col & 31;
        *(unsigned int*)((char*)vf +
                         (((((size_t)b * 8 + head) * 32 + d) * 1024) + n0 +
                          rp * 2) * 2) = val;
      }
    }
  }
}

// ---------------------------------------------------------------------------
// attn_mfma: flash attention, one-pass fixed-max softmax (unchanged R4).
// grid (16 qtiles, 8 heads, 16 batch) x 256.
// ---------------------------------------------------------------------------
__global__ __launch_bounds__(256) void attn_mfma(
    const half_t* __restrict__ qf, const half_t* __restrict__ kf,
    const half_t* __restrict__ vf, const float* __restrict__ tabh,
    const float* __restrict__ lscale, half_t* __restrict__ ao) {
  __shared__ half_t kb[64 * 40];      // k tile [key][dim], stride 40
  __shared__ half_t vt[32 * 72];      // v tile [dim][key], stride 72
  __shared__ half_t pa[4 * 16 * 72];  // P~ per wave [qrow][key], stride 72
  __shared__ float sbias[192];        // 3 x 63 rel-pos bias entries

  int t = threadIdx.x;
  int lane = t & 63, wv = t >> 6, l = lane & 15, quad = lane >> 4;
  int qt = blockIdx.x, h = blockIdx.y, b = blockIdx.z;
  int n0 = qt * 64;
  size_t bh = (size_t)b * 8 + h;
  float scale = __expf(fminf(lscale[h], 4.6051702f));
  float c14 = 14.0f - (scale + 16.0f) * 1.44269504f;

  half8 qfr =
      *(const half8*)(qf + (bh * 1024 + n0 + wv * 16 + l) * 32 + quad * 8);

  int qrow_loc = wv * 16 + l;
  int iwq = qrow_loc & 31;
  int ihl = qrow_loc >> 5;

  float run_l = 0.0f;
  float4v o0 = {0.f, 0.f, 0.f, 0.f}, o1 = {0.f, 0.f, 0.f, 0.f};
  half_t* paw = pa + wv * 16 * 72;

  int key_s = t >> 2, dg_s = t & 3;
  int vd_s = t >> 3, kg_s = t & 7;
  int r3 = (t >= 126) ? 2 : ((t >= 63) ? 1 : 0);
  int pw_s = t - r3 * 63;

  half8 kreg = *(const half8*)(kf + (bh * 1024 + key_s) * 32 + dg_s * 8);
  half8 vreg = *(const half8*)(vf + (bh * 32 + vd_s) * 1024 + kg_s * 8);
  float breg = 0.0f;
  if (t < 189) breg = tabh[h * 3969 + (2 * qt + 30 + r3) * 63 + pw_s];

  for (int kt = 0; kt < 16; kt++) {
    *(half8*)(kb + key_s * 40 + dg_s * 8) = kreg;
    *(half8*)(vt + vd_s * 72 + kg_s * 8) = vreg;
    if (t < 189) sbias[t] = breg;
    __syncthreads();
    if (kt < 15) {
      kreg = *(const half8*)(kf +
                             (bh * 1024 + (kt + 1) * 64 + key_s) * 32 +
                             dg_s * 8);
      vreg = *(const half8*)(vf + (bh * 32 + vd_s) * 1024 + (kt + 1) * 64 +
                             kg_s * 8);
      if (t < 189)
        breg = tabh[h * 3969 + (2 * (qt - kt - 1) + 30 + r3) * 63 + pw_s];
    }

    float4v s[4];
#pragma unroll
    for (int nt = 0; nt < 4; nt++) {
      int base = (ihl - (nt >> 1) + 1) * 63 + iwq + 31 -
                 ((nt & 1) * 16 + 4 * quad);
      float4v c;
      c[0] = sbias[base];
      c[1] = sbias[base - 1];
      c[2] = sbias[base - 2];
      c[3] = sbias[base - 3];
      half8 kfr = *(const half8*)(kb + (nt * 16 + l) * 40 + quad * 8);
      s[nt] = mfma16(kfr, qfr, c);
    }
#pragma unroll
    for (int nt = 0; nt < 4; nt++) {
      half4 ph;
#pragma unroll
      for (int r2 = 0; r2 < 4; r2++) {
        float p = exp2f(fmaf(s[nt][r2], 1.44269504f, c14));
        run_l += p;
        ph[r2] = (half_t)p;
      }
      *(half4*)(paw + l * 72 + nt * 16 + quad * 4) = ph;
    }
#pragma unroll
    for (int ks = 0; ks < 2; ks++) {
      half8 pfr = *(const half8*)(paw + l * 72 + ks * 32 + quad * 8);
      half8 v0f = *(const half8*)(vt + l * 72 + ks * 32 + quad * 8);
      half8 v1f = *(const half8*)(vt + (16 + l) * 72 + ks * 32 + quad * 8);
      o0 = mfma16(pfr, v0f, o0);
      o1 = mfma16(pfr, v1f, o1);
    }
    __syncthreads();
  }

  run_l += __shfl_xor(run_l, 16, 64);
  run_l += __shfl_xor(run_l, 32, 64);
  float rli = 1.0f / run_l;

#pragma unroll
  for (int r2 = 0; r2 < 4; r2++) {
    float linv = __shfl(rli, 20 * quad + r2, 64);
    size_t rowaddr =
        ((size_t)b * 1024 + n0 + wv * 16 + quad * 4 + r2) * 256 + h * 32;
    ao[rowaddr + l] = (half_t)(o0[r2] * linv);
    ao[rowaddr + 16 + l] = (half_t)(o1[r2] * linv);
  }
}

// ---------------------------------------------------------------------------
// proj_mfma: output projection for one half, fp32 out [b][ch][n] via LDS
// transpose.  grid (256, 2) x 256; blockIdx.y = hf.  W staged in LDS.
// ---------------------------------------------------------------------------
__global__ __launch_bounds__(256) void proj_mfma(
    const half_t* __restrict__ ao, const half_t* __restrict__ wp,
    const float* __restrict__ bws, float* __restrict__ out) {
  __shared__ half_t wb[128 * 136];
  __shared__ float yt[128 * 68];
  int t = threadIdx.x;
  int lane = t & 63, wv = t >> 6, l = lane & 15, quad = lane >> 4;
  int hf = blockIdx.y;
  int m0 = blockIdx.x * 64;
  int b = m0 >> 10, n0 = m0 & 1023;

  // stage W
  {
    const half_t* wg = wp + hf * 16384;
#pragma unroll
    for (int i = 0; i < 8; i++) {
      int flat = (t + 256 * i) * 8;
      int row = flat >> 7, col = flat & 127;
      *(half8*)(wb + row * 136 + col) = *(const half8*)(wg + flat);
    }
  }

  half8 afr[4];
  const half_t* ab =
      ao + ((size_t)m0 + wv * 16 + l) * 256 + hf * 128 + quad * 8;
#pragma unroll
  for (int ks = 0; ks < 4; ks++) afr[ks] = *(const half8*)(ab + ks * 32);
  __syncthreads();

#pragma unroll
  for (int ng = 0; ng < 8; ng++) {
    float4v c = {0.f, 0.f, 0.f, 0.f};
#pragma unroll
    for (int ks = 0; ks < 4; ks++)
      c = mfma16(afr[ks],
                 *(const half8*)(wb + (ng * 16 + l) * 136 + ks * 32 +
                                 quad * 8),
                 c);
    float bb = bws[(6 + hf) * 128 + ng * 16 + l];
#pragma unroll
    for (int r2 = 0; r2 < 4; r2++) c[r2] += bb;
    *(float4v*)(yt + (ng * 16 + l) * 68 + wv * 16 + quad * 4) = c;
  }
  __syncthreads();
#pragma unroll
  for (int i = 0; i < 8; i++) {
    int idx = t + 256 * i;
    int col = idx >> 4, rg = idx & 15;
    float4v vv = *(const float4v*)(yt + col * 68 + rg * 4);
    *(float4v*)(out + ((size_t)b * 256 + hf * 128 + col) * 1024 + n0 +
                rg * 4) = vv;
  }
}

// ---------------------------------------------------------------------------
extern "C" void kernel_launch(void* const* d_in, const int* in_sizes, int n_in,
                              void* d_out, int out_size, void* d_ws,
                              size_t ws_size, hipStream_t stream) {
  (void)in_sizes; (void)n_in; (void)out_size; (void)ws_size;
  const float* x = (const float*)d_in[0];

  half_t* ws = (half_t*)d_ws;
  half_t* qfp = ws;                    // [16][8][1024][32] f16
  half_t* kfp = ws + 4194304;          // [16][8][1024][32] f16
  half_t* vfp = ws + 8388608;          // [16][8][32][1024] f16 (transposed)
  half_t* aop = ws + 12582912;         // [16384][256] f16
  half_t* wfp = ws + 16777216;         // 8 x 128x128 f16
  float* tabh = (float*)((char*)d_ws + 33816576);  // [8][3969] f32
  float* bws = (float*)((char*)d_ws + 33943584);   // [8][128] f32

  PtrArr8 wsrc, bsrc;
  const int widx[8] = {1, 3, 5, 7, 9, 11, 13, 15};
  for (int i = 0; i < 8; i++) {
    wsrc.p[i] = (const float*)d_in[widx[i]];
    bsrc.p[i] = (const float*)d_in[widx[i] + 1];
  }

  prep_w<<<dim3(16, 8), 256, 0, stream>>>(wsrc, bsrc, wfp, bws);
  bias_mlp<<<16, 256, 0, stream>>>((const float*)d_in[18],
                                   (const float*)d_in[19],
                                   (const float*)d_in[20], tabh);
  qkv_mfma<<<dim3(256, 2), 256, 0, stream>>>(x, wfp, (const float*)d_in[17],
                                             bws, qfp, kfp, vfp);
  attn_mfma<<<dim3(16, 8, 16), 256, 0, stream>>>(
      qfp, kfp, vfp, tabh, (const float*)d_in[17], aop);
  proj_mfma<<<dim3(256, 2), 256, 0, stream>>>(aop, wfp + 6 * 16384, bws,
                                              (float*)d_out);
}